// Round 11
// baseline (135.481 us; speedup 1.0000x reference)
//
#include <hip/hip_runtime.h>

// SGAN_PoolingNet: pooled[i] = max_j relu( relu([hidden[j], (ends[j]-ends[i])@We+be] @ W1 + b1) @ W2 + b2 )
// Collapse: y_lin[i,j,:] = A[j,:] - U[i,:]
//   A[j,k] = hidden[j]@W1[0:64,k] + ends[j]@M2[:,k] + b1[k] + be@W1[64:80,k]   (f32 math, stored f16)
//   U[i,k] = ends[i]@M2[:,k],  M2 = We @ W1[64:80,:]  (2x128, f32)
// R14: R10 deltas null (93.0 ~ R5 92.2). Budget: fill 40 + pool 27 + prep 4 + ~20 dispatch-stream
//     overhead. Only kernel-controlled overhead left = the prep->pool boundary (dispatch gap +
//     W2T/M2 global round-trip). FUSE into one kernel with a manual grid barrier:
//  (a) grid 512 x 256thr, launch_bounds(256,2): 512 = exactly 2 blocks/CU x 256 CU -> all blocks
//      co-resident (guide par.1 pattern) -> counter-barrier is deadlock-free. Phase1: block b
//      computes A rows 2b,2b+1 (+ W2T,M2 into LDS); threadfence + agent-scope atomicAdd; tid0
//      spins (s_sleep) to 512; phase2 = EXACT R5 pool body (free-running depth-2 ring, no
//      in-loop barriers, no setprio - proven null).
//  (b) W2T (16KB) + M2 (1KB) LDS-local per block: kills their global traffic + prep's
//      32-block special cases. bfrag/upk sourced from LDS once.
//  (c) counter zeroed by 4B hipMemsetAsync on stream (capture-safe; harness memsets likewise).

#define N_AG 1024

typedef __attribute__((ext_vector_type(8))) _Float16 half8;      // 8 f16 = 4 VGPR (MFMA A/B frag)
typedef __attribute__((ext_vector_type(4))) float floatx4;       // MFMA C/D frag
typedef __attribute__((ext_vector_type(4))) unsigned int uintx4; // 4 packed f16 pairs

__device__ __forceinline__ unsigned short f2h(float f) {
  return __builtin_bit_cast(unsigned short, (_Float16)f);   // RNE
}

// d = max(a - u, 0) elementwise on packed f16 pairs: 2 VALU instrs, no unpack.
__device__ __forceinline__ unsigned pk_sub_relu(unsigned a, unsigned u) {
  unsigned d;
  asm("v_pk_add_f16 %0, %1, %2 neg_lo:[0,1] neg_hi:[0,1]\n\t"
      "v_pk_max_f16 %0, %0, 0"
      : "=v"(d) : "v"(a), "v"(u));
  return d;
}

// ---- fused: phase1 = prep (2 A-rows/block, W2T+M2 in LDS); grid barrier; phase2 = pool ----
__global__ __launch_bounds__(256, 2) void fused(
    const float* __restrict__ hidden,  // (1,1024,64)
    const float* __restrict__ track,   // (1024,8,2)
    const float* __restrict__ We,      // (2,16)
    const float* __restrict__ be,      // (16)
    const float* __restrict__ W1,      // (80,128)
    const float* __restrict__ b1,      // (128)
    const float* __restrict__ W2,      // (128,64)
    const float* __restrict__ b2,      // (64)
    unsigned short* __restrict__ Ah,   // ws: (1024,128) f16
    unsigned int* __restrict__ done,   // ws: barrier counter (pre-zeroed)
    float* __restrict__ out)           // (1024,64) f32
{
  const int b   = blockIdx.x;    // 0..511; agents i0=2b,2b+1; produces A rows 2b,2b+1
  const int tid = threadIdx.x;   // 0..255

  __shared__ float hs[2][64];
  __shared__ float M2l[2][128];
  __shared__ __align__(16) unsigned short W2T[64][128];   // 16 KiB
  __shared__ float red[2][4][64];

  // ---- phase 1 ----
  if (tid < 128) hs[tid >> 6][tid & 63] = hidden[b * 128 + tid];
#pragma unroll 8
  for (int q = tid; q < 64 * 128; q += 256) {   // W2T[n][c] = f16(W2[c][n])
    int n = q >> 7, c = q & 127;
    W2T[n][c] = f2h(W2[c * 64 + n]);
  }
  __syncthreads();

  {
    const int col = tid & 127;
    const int row = tid >> 7;          // 2 rows/block, one output elem/thread
    float m20 = 0.f, m21 = 0.f, cb = b1[col];
#pragma unroll
    for (int t = 0; t < 16; ++t) {
      float w1v = W1[(64 + t) * 128 + col];
      m20 += We[t] * w1v;
      m21 += We[16 + t] * w1v;
      cb  += be[t] * w1v;
    }
    const int j = b * 2 + row;
    const float e0 = track[j * 16 + 14];
    const float e1 = track[j * 16 + 15];
    float acc = e0 * m20 + e1 * m21 + cb;
#pragma unroll 8
    for (int t = 0; t < 64; ++t) acc += hs[row][t] * W1[t * 128 + col];
    Ah[j * 128 + col] = f2h(acc);
    if (row == 0) { M2l[0][col] = m20; M2l[1][col] = m21; }
  }

  // ---- manual grid barrier (all 512 blocks co-resident @ 2 blocks/CU) ----
  __syncthreads();                     // block's A stores issued
  if (tid == 0) {
    __threadfence();                   // release A rows to agent scope
    __hip_atomic_fetch_add(done, 1u, __ATOMIC_ACQ_REL, __HIP_MEMORY_SCOPE_AGENT);
    while (__hip_atomic_load(done, __ATOMIC_ACQUIRE, __HIP_MEMORY_SCOPE_AGENT) < 512u)
      __builtin_amdgcn_s_sleep(2);
    __threadfence();                   // acquire: invalidate stale caches before A reads
  }
  __syncthreads();

  // ---- phase 2: R5 pool body (free-running depth-2 register ring) ----
  const int i0   = b * 2;
  const int lane = tid & 63;
  const int w    = tid >> 6;   // wave 0..3: j-tiles jt = 4t + w
  const int m    = lane & 15;  // A row within tile / B-and-D column
  const int quad = lane >> 4;  // k-subrange selector

  const int TSTEP = 4 * 16 * 128;
  const unsigned short* base = Ah + (w * 16 + m) * 128 + quad * 8;

  uintx4 buf0[4], buf1[4];
#pragma unroll
  for (int kk = 0; kk < 4; ++kk) buf0[kk] = *(const uintx4*)(base + kk * 32);
#pragma unroll
  for (int kk = 0; kk < 4; ++kk) buf1[kk] = *(const uintx4*)(base + TSTEP + kk * 32);

  const float a0 = track[i0 * 16 + 14];
  const float a1 = track[i0 * 16 + 15];
  const float c0 = track[(i0 + 1) * 16 + 14];
  const float c1 = track[(i0 + 1) * 16 + 15];
  unsigned upkA[4][4], upkB[4][4];
#pragma unroll
  for (int kk = 0; kk < 4; ++kk) {
#pragma unroll
    for (int p = 0; p < 4; ++p) {
      int k0 = kk * 32 + quad * 8 + 2 * p;
      float m0 = M2l[0][k0],     m0h = M2l[1][k0];
      float m1 = M2l[0][k0 + 1], m1h = M2l[1][k0 + 1];
      upkA[kk][p] = (unsigned)f2h(a0 * m0 + a1 * m0h) | ((unsigned)f2h(a0 * m1 + a1 * m1h) << 16);
      upkB[kk][p] = (unsigned)f2h(c0 * m0 + c1 * m0h) | ((unsigned)f2h(c0 * m1 + c1 * m1h) << 16);
    }
  }

  half8 bfrag[4][4];
#pragma unroll
  for (int nt = 0; nt < 4; ++nt)
#pragma unroll
    for (int kk = 0; kk < 4; ++kk)
      bfrag[nt][kk] = *(const half8*)&W2T[nt * 16 + m][kk * 32 + quad * 8];

  floatx4 mxA[4], mxB[4];
#pragma unroll
  for (int nt = 0; nt < 4; ++nt) {
    mxA[nt] = (floatx4){-3e38f, -3e38f, -3e38f, -3e38f};
    mxB[nt] = (floatx4){-3e38f, -3e38f, -3e38f, -3e38f};
  }

  const unsigned short* pn = base + 2 * TSTEP;

  auto body = [&](uintx4 (&BUF)[4], bool do_load) {
    uintx4 au[4];
#pragma unroll
    for (int kk = 0; kk < 4; ++kk)
#pragma unroll
      for (int p = 0; p < 4; ++p) au[kk][p] = pk_sub_relu(BUF[kk][p], upkA[kk][p]);
#pragma unroll
    for (int nt = 0; nt < 4; ++nt) {
      floatx4 acc = (floatx4){0.f, 0.f, 0.f, 0.f};
#pragma unroll
      for (int kk = 0; kk < 4; ++kk)
        acc = __builtin_amdgcn_mfma_f32_16x16x32_f16(
            __builtin_bit_cast(half8, au[kk]), bfrag[nt][kk], acc, 0, 0, 0);
#pragma unroll
      for (int r = 0; r < 4; ++r) mxA[nt][r] = fmaxf(mxA[nt][r], acc[r]);
    }
#pragma unroll
    for (int kk = 0; kk < 4; ++kk)
#pragma unroll
      for (int p = 0; p < 4; ++p) au[kk][p] = pk_sub_relu(BUF[kk][p], upkB[kk][p]);
    if (do_load) {
#pragma unroll
      for (int kk = 0; kk < 4; ++kk) BUF[kk] = *(const uintx4*)(pn + kk * 32);
      pn += TSTEP;
    }
#pragma unroll
    for (int nt = 0; nt < 4; ++nt) {
      floatx4 acc = (floatx4){0.f, 0.f, 0.f, 0.f};
#pragma unroll
      for (int kk = 0; kk < 4; ++kk)
        acc = __builtin_amdgcn_mfma_f32_16x16x32_f16(
            __builtin_bit_cast(half8, au[kk]), bfrag[nt][kk], acc, 0, 0, 0);
#pragma unroll
      for (int r = 0; r < 4; ++r) mxB[nt][r] = fmaxf(mxB[nt][r], acc[r]);
    }
  };

#pragma unroll 1
  for (int t2 = 0; t2 < 14; t2 += 2) {
    body(buf0, true);
    body(buf1, true);
  }
  body(buf0, false);   // t=14
  body(buf1, false);   // t=15

  // reduce: rows in-lane, quads via shfl, j-waves via LDS; two agents side by side
#pragma unroll
  for (int nt = 0; nt < 4; ++nt) {
    float a = fmaxf(fmaxf(mxA[nt][0], mxA[nt][1]), fmaxf(mxA[nt][2], mxA[nt][3]));
    a = fmaxf(a, __shfl_xor(a, 16, 64));
    a = fmaxf(a, __shfl_xor(a, 32, 64));
    float bb = fmaxf(fmaxf(mxB[nt][0], mxB[nt][1]), fmaxf(mxB[nt][2], mxB[nt][3]));
    bb = fmaxf(bb, __shfl_xor(bb, 16, 64));
    bb = fmaxf(bb, __shfl_xor(bb, 32, 64));
    if (quad == 0) {
      red[0][w][nt * 16 + m] = a;
      red[1][w][nt * 16 + m] = bb;
    }
  }
  __syncthreads();
  if (tid < 128) {
    int g = tid >> 6, n = tid & 63;
    float v = fmaxf(fmaxf(red[g][0][n], red[g][1][n]), fmaxf(red[g][2][n], red[g][3][n]));
    v += b2[n];
    out[(i0 + g) * 64 + n] = v > 0.f ? v : 0.f;
  }
}

extern "C" void kernel_launch(void* const* d_in, const int* in_sizes, int n_in,
                              void* d_out, int out_size, void* d_ws, size_t ws_size,
                              hipStream_t stream) {
  const float* hidden = (const float*)d_in[0]; // (1,1024,64)
  const float* track  = (const float*)d_in[1]; // (1024,8,2)
  const float* We     = (const float*)d_in[2]; // (2,16)
  const float* be     = (const float*)d_in[3]; // (16)
  const float* W1     = (const float*)d_in[4]; // (80,128)
  const float* b1     = (const float*)d_in[5]; // (128)
  const float* W2     = (const float*)d_in[6]; // (128,64)
  const float* b2     = (const float*)d_in[7]; // (64)
  float* out = (float*)d_out;

  char* ws = (char*)d_ws;
  unsigned short* Ah   = (unsigned short*)ws;          // 1024*128*2 = 256 KiB
  unsigned int*   done = (unsigned int*)(ws + 262144); // 4 B barrier counter

  hipMemsetAsync(done, 0, 4, stream);                  // stream-ordered, capture-safe
  fused<<<N_AG / 2, 256, 0, stream>>>(hidden, track, We, be, W1, b1, W2, b2, Ah, done, out);
}

// Round 12
// 130.314 us; speedup vs baseline: 1.0397x; 1.0397x over previous
//
#include <hip/hip_runtime.h>

// SGAN_PoolingNet: pooled[i] = max_j relu( relu([hidden[j], (ends[j]-ends[i])@We+be] @ W1 + b1) @ W2 + b2 )
// Collapse: y_lin[i,j,:] = A[j,:] - U[i,:]
//   A[j,k] = hidden[j]@W1[0:64,k] + ends[j]@M2[:,k] + b1[k] + be@W1[64:80,k]   (f32 math, stored f16)
//   U[i,k] = ends[i]@M2[:,k],  M2 = We @ W1[64:80,:]  (2x128, f32)
// R15: R14 fused regressed (79us vs pool 27) -- counters localized 3 implementation bugs, not
//     the fusion concept: (1) Ah stored with PLAIN stores (NT dropped in rewrite) -> dirty lines
//     in 8 XCDs' L2s -> phase2 cross-XCD dirty-snoop on every A line; (2) W2 transpose fill read
//     W2[c*64+n] as a 64-line gather per wave-load (TA-bound); (3) W2T[64][128] LDS: 256B row
//     stride -> 16-way bank conflict on bfrag reads (SQ_LDS_BANK_CONFLICT 917K). Fixes:
//  (a) __builtin_nontemporal_store for Ah (restores R5 behavior; fence still orders visibility);
//  (b) coalesced float4 reads of W2 (linear index), transposed scatter into LDS;
//  (c) W2T padded to [64][136]: 272B stride, 16B-aligned rows, ~2-4-way worst case.
//     Barrier/residency machinery unchanged (proven correct in R14).

#define N_AG 1024

typedef __attribute__((ext_vector_type(8))) _Float16 half8;      // 8 f16 = 4 VGPR (MFMA A/B frag)
typedef __attribute__((ext_vector_type(4))) float floatx4;       // MFMA C/D frag
typedef __attribute__((ext_vector_type(4))) unsigned int uintx4; // 4 packed f16 pairs

__device__ __forceinline__ unsigned short f2h(float f) {
  return __builtin_bit_cast(unsigned short, (_Float16)f);   // RNE
}

// d = max(a - u, 0) elementwise on packed f16 pairs: 2 VALU instrs, no unpack.
__device__ __forceinline__ unsigned pk_sub_relu(unsigned a, unsigned u) {
  unsigned d;
  asm("v_pk_add_f16 %0, %1, %2 neg_lo:[0,1] neg_hi:[0,1]\n\t"
      "v_pk_max_f16 %0, %0, 0"
      : "=v"(d) : "v"(a), "v"(u));
  return d;
}

// ---- fused: phase1 = prep (2 A-rows/block, W2T+M2 in LDS); grid barrier; phase2 = pool ----
__global__ __launch_bounds__(256, 2) void fused(
    const float* __restrict__ hidden,  // (1,1024,64)
    const float* __restrict__ track,   // (1024,8,2)
    const float* __restrict__ We,      // (2,16)
    const float* __restrict__ be,      // (16)
    const float* __restrict__ W1,      // (80,128)
    const float* __restrict__ b1,      // (128)
    const float* __restrict__ W2,      // (128,64)
    const float* __restrict__ b2,      // (64)
    unsigned short* __restrict__ Ah,   // ws: (1024,128) f16
    unsigned int* __restrict__ done,   // ws: barrier counter (pre-zeroed)
    float* __restrict__ out)           // (1024,64) f32
{
  const int b   = blockIdx.x;    // 0..511; agents i0=2b,2b+1; produces A rows 2b,2b+1
  const int tid = threadIdx.x;   // 0..255

  __shared__ float hs[2][64];
  __shared__ float M2l[2][128];
  __shared__ __align__(16) unsigned short W2T[64][136];   // padded: 272B row stride
  __shared__ float red[2][4][64];

  // ---- phase 1 ----
  if (tid < 128) hs[tid >> 6][tid & 63] = hidden[b * 128 + tid];
  // W2T[n][c] = f16(W2[c][n]); coalesced float4 reads (linear), transposed LDS writes
#pragma unroll
  for (int it = 0; it < 8; ++it) {
    int e = (it * 256 + tid) * 4;        // element index in W2 = c*64 + n
    floatx4 v = *(const floatx4*)(W2 + e);
    int c = e >> 6, n = e & 63;
#pragma unroll
    for (int jj = 0; jj < 4; ++jj) W2T[n + jj][c] = f2h(v[jj]);
  }
  __syncthreads();

  {
    const int col = tid & 127;
    const int row = tid >> 7;          // 2 rows/block, one output elem/thread
    float m20 = 0.f, m21 = 0.f, cb = b1[col];
#pragma unroll
    for (int t = 0; t < 16; ++t) {
      float w1v = W1[(64 + t) * 128 + col];
      m20 += We[t] * w1v;
      m21 += We[16 + t] * w1v;
      cb  += be[t] * w1v;
    }
    const int j = b * 2 + row;
    const float e0 = track[j * 16 + 14];
    const float e1 = track[j * 16 + 15];
    float acc = e0 * m20 + e1 * m21 + cb;
#pragma unroll 8
    for (int t = 0; t < 64; ++t) acc += hs[row][t] * W1[t * 128 + col];
    __builtin_nontemporal_store(f2h(acc), &Ah[j * 128 + col]);   // NT: no dirty-L2 bounce
    if (row == 0) { M2l[0][col] = m20; M2l[1][col] = m21; }
  }

  // ---- manual grid barrier (all 512 blocks co-resident @ 2 blocks/CU) ----
  __syncthreads();                     // block's A stores issued
  if (tid == 0) {
    __threadfence();                   // release A rows to agent scope
    __hip_atomic_fetch_add(done, 1u, __ATOMIC_ACQ_REL, __HIP_MEMORY_SCOPE_AGENT);
    while (__hip_atomic_load(done, __ATOMIC_ACQUIRE, __HIP_MEMORY_SCOPE_AGENT) < 512u)
      __builtin_amdgcn_s_sleep(2);
    __threadfence();                   // acquire: invalidate stale caches before A reads
  }
  __syncthreads();

  // ---- phase 2: R5 pool body (free-running depth-2 register ring) ----
  const int i0   = b * 2;
  const int lane = tid & 63;
  const int w    = tid >> 6;   // wave 0..3: j-tiles jt = 4t + w
  const int m    = lane & 15;  // A row within tile / B-and-D column
  const int quad = lane >> 4;  // k-subrange selector

  const int TSTEP = 4 * 16 * 128;
  const unsigned short* base = Ah + (w * 16 + m) * 128 + quad * 8;

  uintx4 buf0[4], buf1[4];
#pragma unroll
  for (int kk = 0; kk < 4; ++kk) buf0[kk] = *(const uintx4*)(base + kk * 32);
#pragma unroll
  for (int kk = 0; kk < 4; ++kk) buf1[kk] = *(const uintx4*)(base + TSTEP + kk * 32);

  const float a0 = track[i0 * 16 + 14];
  const float a1 = track[i0 * 16 + 15];
  const float c0 = track[(i0 + 1) * 16 + 14];
  const float c1 = track[(i0 + 1) * 16 + 15];
  unsigned upkA[4][4], upkB[4][4];
#pragma unroll
  for (int kk = 0; kk < 4; ++kk) {
#pragma unroll
    for (int p = 0; p < 4; ++p) {
      int k0 = kk * 32 + quad * 8 + 2 * p;
      float m0 = M2l[0][k0],     m0h = M2l[1][k0];
      float m1 = M2l[0][k0 + 1], m1h = M2l[1][k0 + 1];
      upkA[kk][p] = (unsigned)f2h(a0 * m0 + a1 * m0h) | ((unsigned)f2h(a0 * m1 + a1 * m1h) << 16);
      upkB[kk][p] = (unsigned)f2h(c0 * m0 + c1 * m0h) | ((unsigned)f2h(c0 * m1 + c1 * m1h) << 16);
    }
  }

  half8 bfrag[4][4];
#pragma unroll
  for (int nt = 0; nt < 4; ++nt)
#pragma unroll
    for (int kk = 0; kk < 4; ++kk)
      bfrag[nt][kk] = *(const half8*)&W2T[nt * 16 + m][kk * 32 + quad * 8];

  floatx4 mxA[4], mxB[4];
#pragma unroll
  for (int nt = 0; nt < 4; ++nt) {
    mxA[nt] = (floatx4){-3e38f, -3e38f, -3e38f, -3e38f};
    mxB[nt] = (floatx4){-3e38f, -3e38f, -3e38f, -3e38f};
  }

  const unsigned short* pn = base + 2 * TSTEP;

  auto body = [&](uintx4 (&BUF)[4], bool do_load) {
    uintx4 au[4];
#pragma unroll
    for (int kk = 0; kk < 4; ++kk)
#pragma unroll
      for (int p = 0; p < 4; ++p) au[kk][p] = pk_sub_relu(BUF[kk][p], upkA[kk][p]);
#pragma unroll
    for (int nt = 0; nt < 4; ++nt) {
      floatx4 acc = (floatx4){0.f, 0.f, 0.f, 0.f};
#pragma unroll
      for (int kk = 0; kk < 4; ++kk)
        acc = __builtin_amdgcn_mfma_f32_16x16x32_f16(
            __builtin_bit_cast(half8, au[kk]), bfrag[nt][kk], acc, 0, 0, 0);
#pragma unroll
      for (int r = 0; r < 4; ++r) mxA[nt][r] = fmaxf(mxA[nt][r], acc[r]);
    }
#pragma unroll
    for (int kk = 0; kk < 4; ++kk)
#pragma unroll
      for (int p = 0; p < 4; ++p) au[kk][p] = pk_sub_relu(BUF[kk][p], upkB[kk][p]);
    if (do_load) {
#pragma unroll
      for (int kk = 0; kk < 4; ++kk) BUF[kk] = *(const uintx4*)(pn + kk * 32);
      pn += TSTEP;
    }
#pragma unroll
    for (int nt = 0; nt < 4; ++nt) {
      floatx4 acc = (floatx4){0.f, 0.f, 0.f, 0.f};
#pragma unroll
      for (int kk = 0; kk < 4; ++kk)
        acc = __builtin_amdgcn_mfma_f32_16x16x32_f16(
            __builtin_bit_cast(half8, au[kk]), bfrag[nt][kk], acc, 0, 0, 0);
#pragma unroll
      for (int r = 0; r < 4; ++r) mxB[nt][r] = fmaxf(mxB[nt][r], acc[r]);
    }
  };

#pragma unroll 1
  for (int t2 = 0; t2 < 14; t2 += 2) {
    body(buf0, true);
    body(buf1, true);
  }
  body(buf0, false);   // t=14
  body(buf1, false);   // t=15

  // reduce: rows in-lane, quads via shfl, j-waves via LDS; two agents side by side
#pragma unroll
  for (int nt = 0; nt < 4; ++nt) {
    float a = fmaxf(fmaxf(mxA[nt][0], mxA[nt][1]), fmaxf(mxA[nt][2], mxA[nt][3]));
    a = fmaxf(a, __shfl_xor(a, 16, 64));
    a = fmaxf(a, __shfl_xor(a, 32, 64));
    float bb = fmaxf(fmaxf(mxB[nt][0], mxB[nt][1]), fmaxf(mxB[nt][2], mxB[nt][3]));
    bb = fmaxf(bb, __shfl_xor(bb, 16, 64));
    bb = fmaxf(bb, __shfl_xor(bb, 32, 64));
    if (quad == 0) {
      red[0][w][nt * 16 + m] = a;
      red[1][w][nt * 16 + m] = bb;
    }
  }
  __syncthreads();
  if (tid < 128) {
    int g = tid >> 6, n = tid & 63;
    float v = fmaxf(fmaxf(red[g][0][n], red[g][1][n]), fmaxf(red[g][2][n], red[g][3][n]));
    v += b2[n];
    out[(i0 + g) * 64 + n] = v > 0.f ? v : 0.f;
  }
}

extern "C" void kernel_launch(void* const* d_in, const int* in_sizes, int n_in,
                              void* d_out, int out_size, void* d_ws, size_t ws_size,
                              hipStream_t stream) {
  const float* hidden = (const float*)d_in[0]; // (1,1024,64)
  const float* track  = (const float*)d_in[1]; // (1024,8,2)
  const float* We     = (const float*)d_in[2]; // (2,16)
  const float* be     = (const float*)d_in[3]; // (16)
  const float* W1     = (const float*)d_in[4]; // (80,128)
  const float* b1     = (const float*)d_in[5]; // (128)
  const float* W2     = (const float*)d_in[6]; // (128,64)
  const float* b2     = (const float*)d_in[7]; // (64)
  float* out = (float*)d_out;

  char* ws = (char*)d_ws;
  unsigned short* Ah   = (unsigned short*)ws;          // 1024*128*2 = 256 KiB
  unsigned int*   done = (unsigned int*)(ws + 262144); // 4 B barrier counter

  hipMemsetAsync(done, 0, 4, stream);                  // stream-ordered, capture-safe
  fused<<<N_AG / 2, 256, 0, stream>>>(hidden, track, We, be, W1, b1, W2, b2, Ah, done, out);
}

// Round 14
// 93.654 us; speedup vs baseline: 1.4466x; 1.3914x over previous
//
#include <hip/hip_runtime.h>

// SGAN_PoolingNet: pooled[i] = max_j relu( relu([hidden[j], (ends[j]-ends[i])@We+be] @ W1 + b1) @ W2 + b2 )
// Collapse: y_lin[i,j,:] = A[j,:] - U[i,:]
//   A[j,k] = hidden[j]@W1[0:64,k] + ends[j]@M2[:,k] + b1[k] + be@W1[64:80,k]   (f32 math, stored f16)
//   U[i,k] = ends[i]@M2[:,k],  M2 = We @ W1[64:80,:]  (2x128, f32)
// R17 == R16 resubmit (R16 bench was an infra failure, no counters; source audited in-bounds,
//     barrier-uniform, constant loop trip counts -- cannot hang/fault):
//     fusion abandoned (R14 79us, R15 67us vs two-kernel 31us). Pool insight: with G=2 each A
//     line is read exactly once per block -- only MORE AGENTS PER TILE cuts traffic. G=4 @
//     2 waves/SIMD = ~255 regs = spill cliff -> G=4 FAT-WAVE: 256 blocks x 256thr (4 waves,
//     j-split 4-way), launch_bounds(256,1) -> 1 wave/SIMD, 512-reg budget (~280 used, no spill),
//     grid = exactly 1 block/CU. Latency hiding = pure ILP: depth-3 ring (~1200cy coverage >
//     900cy HBM class), per-tile compute x2 (4 repacks + 64 MFMA). Traffic 128->64 MB.
//     Free-running: no in-loop barriers (the one property that consistently won).

#define N_AG 1024
#define JT 4

typedef __attribute__((ext_vector_type(8))) _Float16 half8;      // 8 f16 = 4 VGPR (MFMA A/B frag)
typedef __attribute__((ext_vector_type(4))) float floatx4;       // MFMA C/D frag
typedef __attribute__((ext_vector_type(4))) unsigned int uintx4; // 4 packed f16 pairs

__device__ __forceinline__ unsigned short f2h(float f) {
  return __builtin_bit_cast(unsigned short, (_Float16)f);   // RNE
}

// d = max(a - u, 0) elementwise on packed f16 pairs: 2 VALU instrs, no unpack.
__device__ __forceinline__ unsigned pk_sub_relu(unsigned a, unsigned u) {
  unsigned d;
  asm("v_pk_add_f16 %0, %1, %2 neg_lo:[0,1] neg_hi:[0,1]\n\t"
      "v_pk_max_f16 %0, %0, 0"
      : "=v"(d) : "v"(a), "v"(u));
  return d;
}

// ---- prep (R5-exact): block jb computes A[4jb..4jb+3]; block 0 writes M2; blocks 0..31 W2T ----
__global__ __launch_bounds__(128) void prep_all(
    const float* __restrict__ hidden,  // (1,1024,64)
    const float* __restrict__ track,   // (1024,8,2)
    const float* __restrict__ We,      // (2,16)
    const float* __restrict__ be,      // (16)
    const float* __restrict__ W1,      // (80,128)
    const float* __restrict__ b1,      // (128)
    const float* __restrict__ W2,      // (128,64)
    unsigned short* __restrict__ Ah,   // (1024,128) f16
    float* __restrict__ M2f,           // (2,128) f32
    unsigned short* __restrict__ W2T)  // (64,128) f16
{
  const int jb = blockIdx.x;          // 0..255
  const int j0 = jb * JT;
  const int k  = threadIdx.x;         // 0..127
  __shared__ float hs[JT][64];
#pragma unroll
  for (int q = k; q < JT * 64; q += 128) hs[q >> 6][q & 63] = hidden[j0 * 64 + q];
  __syncthreads();

  float m20 = 0.f, m21 = 0.f, cb = b1[k];
#pragma unroll
  for (int t = 0; t < 16; ++t) {
    float w1v = W1[(64 + t) * 128 + k];
    m20 += We[t] * w1v;
    m21 += We[16 + t] * w1v;
    cb  += be[t] * w1v;
  }
  float acc[JT];
#pragma unroll
  for (int jj = 0; jj < JT; ++jj) {
    float e0 = track[(j0 + jj) * 16 + 14];
    float e1 = track[(j0 + jj) * 16 + 15];
    acc[jj] = e0 * m20 + e1 * m21 + cb;
  }
#pragma unroll 8
  for (int t = 0; t < 64; ++t) {
    float w = W1[t * 128 + k];
#pragma unroll
    for (int jj = 0; jj < JT; ++jj) acc[jj] += hs[jj][t] * w;
  }
#pragma unroll
  for (int jj = 0; jj < JT; ++jj)
    __builtin_nontemporal_store(f2h(acc[jj]), &Ah[(j0 + jj) * 128 + k]);

  if (jb == 0) {          // m20/m21 are exactly M2[0][k], M2[1][k]
    M2f[k]       = m20;
    M2f[128 + k] = m21;
  }
  if (jb < 32) {          // W2T[n][c] = f16(W2[c][n]); 32 blocks x 256 entries
#pragma unroll
    for (int q = 0; q < 2; ++q) {
      int idx = jb * 256 + q * 128 + k;
      int n = idx >> 7, c = idx & 127;
      W2T[n * 128 + c] = f2h(W2[c * 64 + n]);
    }
  }
}

// ---- main: one block per 4 agents; 4 fat waves (1/SIMD), j-split 4-way, depth-3 ring ----
__global__ __launch_bounds__(256, 1) void pool_main(
    const unsigned short* __restrict__ Ah,    // (1024,128) f16
    const float* __restrict__ M2f,            // (2,128) f32
    const float* __restrict__ track,          // (1024,8,2) f32
    const unsigned short* __restrict__ W2T,   // (64,128) f16
    const float* __restrict__ b2,             // (64) f32
    float* __restrict__ out)                  // (1024,64) f32
{
  const int i0   = blockIdx.x * 4;
  const int lane = threadIdx.x & 63;
  const int w    = threadIdx.x >> 6;   // wave 0..3: j-tiles jt = 4t + w
  const int m    = lane & 15;          // A row within tile / B-and-D column
  const int quad = lane >> 4;          // k-subrange selector

  const int TSTEP = 4 * 16 * 128;      // elems between this wave's consecutive tiles
  const unsigned short* base = Ah + (w * 16 + m) * 128 + quad * 8;

  // depth-3 register ring: issue tiles 0,1,2 ASAP
  uintx4 buf0[4], buf1[4], buf2[4];
#pragma unroll
  for (int kk = 0; kk < 4; ++kk) buf0[kk] = *(const uintx4*)(base + kk * 32);
#pragma unroll
  for (int kk = 0; kk < 4; ++kk) buf1[kk] = *(const uintx4*)(base + TSTEP + kk * 32);
#pragma unroll
  for (int kk = 0; kk < 4; ++kk) buf2[kk] = *(const uintx4*)(base + 2 * TSTEP + kk * 32);

  // U[i0..i0+3] as packed f16 pairs matching A's dword element order (f32 math, as R5)
  float e0[4], e1[4];
#pragma unroll
  for (int g = 0; g < 4; ++g) {
    e0[g] = track[(i0 + g) * 16 + 14];
    e1[g] = track[(i0 + g) * 16 + 15];
  }
  unsigned upk[4][4][4];               // [agent][kk][p] = 64 VGPR
#pragma unroll
  for (int kk = 0; kk < 4; ++kk) {
#pragma unroll
    for (int p = 0; p < 4; ++p) {
      int k0 = kk * 32 + quad * 8 + 2 * p;
      float m0 = M2f[k0],     m0h = M2f[128 + k0];
      float m1 = M2f[k0 + 1], m1h = M2f[128 + k0 + 1];
#pragma unroll
      for (int g = 0; g < 4; ++g)
        upk[g][kk][p] = (unsigned)f2h(e0[g] * m0 + e1[g] * m0h) |
                        ((unsigned)f2h(e0[g] * m1 + e1[g] * m1h) << 16);
    }
  }

  // full 64-col B panel (4 x 16-col blocks), register/AGPR-resident
  half8 bfrag[4][4];
#pragma unroll
  for (int nt = 0; nt < 4; ++nt)
#pragma unroll
    for (int kk = 0; kk < 4; ++kk)
      bfrag[nt][kk] = *(const half8*)(W2T + (nt * 16 + m) * 128 + kk * 32 + quad * 8);

  floatx4 mx[4][4];                    // [agent][nt] = 64 VGPR
#pragma unroll
  for (int g = 0; g < 4; ++g)
#pragma unroll
    for (int nt = 0; nt < 4; ++nt) mx[g][nt] = (floatx4){-3e38f, -3e38f, -3e38f, -3e38f};

  const unsigned short* pn = base + 3 * TSTEP;   // next tile to load (t+3)

  // body: 4 agents x {repack + 16 MFMA}; prefetch into BUF after its LAST repack use (g=3).
  auto body = [&](uintx4 (&BUF)[4], bool do_load) {
#pragma unroll
    for (int g = 0; g < 4; ++g) {
      uintx4 au[4];
#pragma unroll
      for (int kk = 0; kk < 4; ++kk)
#pragma unroll
        for (int p = 0; p < 4; ++p) au[kk][p] = pk_sub_relu(BUF[kk][p], upk[g][kk][p]);
      if (g == 3 && do_load) {
#pragma unroll
        for (int kk = 0; kk < 4; ++kk) BUF[kk] = *(const uintx4*)(pn + kk * 32);
        pn += TSTEP;
      }
#pragma unroll
      for (int nt = 0; nt < 4; ++nt) {
        floatx4 acc = (floatx4){0.f, 0.f, 0.f, 0.f};
#pragma unroll
        for (int kk = 0; kk < 4; ++kk)
          acc = __builtin_amdgcn_mfma_f32_16x16x32_f16(
              __builtin_bit_cast(half8, au[kk]), bfrag[nt][kk], acc, 0, 0, 0);
#pragma unroll
        for (int r = 0; r < 4; ++r) mx[g][nt][r] = fmaxf(mx[g][nt][r], acc[r]);
      }
    }
  };

  // 16 tiles/wave, depth-3 ring: 4x{b0,b1,b2} loading t+3 (t=0..11 -> loads 3..14),
  // then t=12 (loads 15 into b0), t=13, t=14, t=15 drain.
#pragma unroll 1
  for (int t3 = 0; t3 < 4; ++t3) {
    body(buf0, true);
    body(buf1, true);
    body(buf2, true);
  }
  body(buf0, true);    // t=12, loads t=15 into buf0
  body(buf1, false);   // t=13
  body(buf2, false);   // t=14
  body(buf0, false);   // t=15

  // D layout: row = quad*4 + r (j within tile), col = nt*16 + m. Reduce rows in-lane,
  // quads via shfl, the 4 j-waves via LDS; 4 agents independent.
  __shared__ float red[4][4][64];      // [wave][agent][col] = 4 KiB
#pragma unroll
  for (int g = 0; g < 4; ++g)
#pragma unroll
    for (int nt = 0; nt < 4; ++nt) {
      float a = fmaxf(fmaxf(mx[g][nt][0], mx[g][nt][1]), fmaxf(mx[g][nt][2], mx[g][nt][3]));
      a = fmaxf(a, __shfl_xor(a, 16, 64));
      a = fmaxf(a, __shfl_xor(a, 32, 64));
      if (quad == 0) red[w][g][nt * 16 + m] = a;
    }
  __syncthreads();
  {
    int g = threadIdx.x >> 6, n = threadIdx.x & 63;   // all 256 threads: 4 agents x 64 cols
    float v = fmaxf(fmaxf(red[0][g][n], red[1][g][n]), fmaxf(red[2][g][n], red[3][g][n]));
    v += b2[n];
    out[(i0 + g) * 64 + n] = v > 0.f ? v : 0.f;
  }
}

extern "C" void kernel_launch(void* const* d_in, const int* in_sizes, int n_in,
                              void* d_out, int out_size, void* d_ws, size_t ws_size,
                              hipStream_t stream) {
  const float* hidden = (const float*)d_in[0]; // (1,1024,64)
  const float* track  = (const float*)d_in[1]; // (1024,8,2)
  const float* We     = (const float*)d_in[2]; // (2,16)
  const float* be     = (const float*)d_in[3]; // (16)
  const float* W1     = (const float*)d_in[4]; // (80,128)
  const float* b1     = (const float*)d_in[5]; // (128)
  const float* W2     = (const float*)d_in[6]; // (128,64)
  const float* b2     = (const float*)d_in[7]; // (64)
  float* out = (float*)d_out;

  char* ws = (char*)d_ws;
  unsigned short* Ah  = (unsigned short*)ws;              // 1024*128*2 = 256 KiB
  float*          M2f = (float*)(ws + 262144);            // 256*4     = 1 KiB
  unsigned short* W2T = (unsigned short*)(ws + 263168);   // 64*128*2  = 16 KiB

  prep_all<<<N_AG / JT, 128, 0, stream>>>(hidden, track, We, be, W1, b1, W2, Ah, M2f, W2T);
  pool_main<<<N_AG / 4, 256, 0, stream>>>(Ah, M2f, track, W2T, b2, out);
}